// Round 5
// baseline (410.003 us; speedup 1.0000x reference)
//
#include <hip/hip_runtime.h>
#include <hip/hip_bf16.h>
#include <stdint.h>

// GORU fused cell. B=8192, IN=1024, D=1024, CAP=10.
// 3 launches:
//   prep_all : xs[8192][2048] bf16 = [bf16(x)|bf16(state)];
//              Wt0[1024][1024]=U_c^T; Wt12[2048][2048]=[[U_r^T|W_r^T],[U_g^T|W_g^T]];
//              v1/v2[10][1024] butterfly tables
//   gemm     : P[8192][3072] bf16 = { Ucx , interleaved (r,g) }
//              rg-MERGED blocks: one A-tile staged, two B tiles, 32 MFMA/barrier,
//              packed 4B (r,g) stores. Ucx blocks: 16 MFMA/barrier, K=1024.
//              BK=32, zero-conflict XOR swizzle pos = gq ^ ((row>>1)&3).
//   fuse     : out = g*state + (1-g)*modReLU(r*butterfly(state) + Ucx)

typedef __bf16 bf16x8 __attribute__((ext_vector_type(8)));
typedef __bf16 bf16x4 __attribute__((ext_vector_type(4)));
typedef __bf16 bf16x2 __attribute__((ext_vector_type(2)));
typedef float f32x4 __attribute__((ext_vector_type(4)));

#define B_ROWS 8192

__device__ __forceinline__ void async16(__bf16* lds, const __hip_bfloat16* g) {
    __builtin_amdgcn_global_load_lds((const __attribute__((address_space(1))) void*)g,
                                     (__attribute__((address_space(3))) void*)lds,
                                     16, 0, 0);
}

// ---------------- prep_all: blockIdx-partitioned (xs cast | weight transpose | tables) ----------------
__global__ __launch_bounds__(256) void prep_all(const float* __restrict__ x,
                                                const float* __restrict__ state,
                                                const float* __restrict__ theta,
                                                const float* __restrict__ U,
                                                const float* __restrict__ Wr,
                                                const float* __restrict__ Wg,
                                                __hip_bfloat16* __restrict__ xs,
                                                __hip_bfloat16* __restrict__ Wt0,
                                                __hip_bfloat16* __restrict__ Wt12,
                                                float* __restrict__ v1,
                                                float* __restrict__ v2) {
    __shared__ float tile[32][33];
    const int id = blockIdx.x;
    if (id < 8192) {
        // --- xs = [bf16(x) | bf16(state)] ---
        const int row = id;
        const int col = threadIdx.x * 8;  // 0..2040
        const float* src = (col < 1024) ? (x + (size_t)row * 1024 + col)
                                        : (state + (size_t)row * 1024 + (col - 1024));
        float4 a = *(const float4*)src;
        float4 b = *(const float4*)(src + 4);
        bf16x8 v;
        v[0] = (__bf16)a.x; v[1] = (__bf16)a.y; v[2] = (__bf16)a.z; v[3] = (__bf16)a.w;
        v[4] = (__bf16)b.x; v[5] = (__bf16)b.y; v[6] = (__bf16)b.z; v[7] = (__bf16)b.w;
        *(bf16x8*)((__bf16*)xs + (size_t)row * 2048 + col) = v;
    } else if (id < 13312) {
        // --- weight transpose+cast ---
        const int wid = id - 8192;
        const float* src; int srcN, scol, sk;
        __hip_bfloat16* dst; int dstStride, dn, dk;
        if (wid < 1024) {
            int nx = wid & 31, ky = wid >> 5;
            src = U; srcN = 3072; scol = nx * 32; sk = ky * 32;
            dst = Wt0; dstStride = 1024; dn = nx * 32; dk = ky * 32;
        } else {
            int id2 = wid - 1024;
            int nx = id2 & 63, ky = id2 >> 6;
            int n0 = nx * 32, k0 = ky * 32;
            dst = Wt12; dstStride = 2048; dn = n0; dk = k0;
            if (k0 < 1024)      { src = U;  srcN = 3072; scol = 1024 + n0; sk = k0; }
            else if (n0 < 1024) { src = Wr; srcN = 1024; scol = n0;        sk = k0 - 1024; }
            else                { src = Wg; srcN = 1024; scol = n0 - 1024; sk = k0 - 1024; }
        }
        const int tx = threadIdx.x & 31, ty = threadIdx.x >> 5;
#pragma unroll
        for (int s = 0; s < 4; ++s)
            tile[ty + s * 8][tx] = src[(size_t)(sk + ty + s * 8) * srcN + scol + tx];
        __syncthreads();
#pragma unroll
        for (int s = 0; s < 4; ++s)
            dst[(size_t)(dn + ty + s * 8) * dstStride + dk + tx] = __float2bfloat16(tile[tx][ty + s * 8]);
    } else {
        // --- butterfly tables ---
        // v1[i][j]=cos(theta[i][q&511]); v2[i][j]=(q<512?+sin:-sin), q=m*2^i+j0,
        // j0=j>>(10-i), m=j&((1024>>i)-1).
        int idx = (id - 13312) * 256 + threadIdx.x;  // 10240 total
        int i = idx >> 10;
        int j = idx & 1023;
        int Q = 1024 >> i;
        int j0 = j / Q;
        int m = j & (Q - 1);
        int q = (m << i) + j0;
        float th = theta[i * 512 + (q & 511)];
        float c = cosf(th);
        float s = sinf(th);
        v1[idx] = c;
        v2[idx] = (q < 512) ? s : -s;
    }
}

// ---------------- GEMM ----------------
// Zero-conflict swizzle: LDS chunk c holds global (row=c>>2, k-chunk (c&3)^((row>>1)&3)).
// Read cc = row*4 + (gq ^ ((row>>1)&3)): bank-quad start 4*(row&1)+(gq^((row>>1)&3)) is a
// bijection on every aligned 8-lane phase group -> zero ds_read_b128 conflicts (verified r4).

// Ucx path: single B tile, K=1024.
__device__ __forceinline__ void kloop_c(const __hip_bfloat16* __restrict__ A,
                                        const __hip_bfloat16* __restrict__ Bb,
                                        __bf16* As, __bf16* Bs, f32x4 acc[4][4],
                                        int t, int wm, int wn, int r0, int gq) {
    for (int k0 = 0; k0 < 1024; k0 += 32) {
#pragma unroll
        for (int p = 0; p < 2; ++p) {
            int c = p * 256 + t;
            int row = c >> 2;
            int jj = ((c & 3) ^ ((row >> 1) & 3)) * 8;
            async16(&As[c * 8], A + (size_t)row * 2048 + k0 + jj);
            async16(&Bs[c * 8], Bb + (size_t)row * 1024 + k0 + jj);
        }
        __syncthreads();
        bf16x8 af[4], bf[4];
#pragma unroll
        for (int i = 0; i < 4; ++i) {
            int row = wm * 64 + i * 16 + r0;
            int cc = row * 4 + (gq ^ ((row >> 1) & 3));
            af[i] = *reinterpret_cast<const bf16x8*>(&As[cc * 8]);
        }
#pragma unroll
        for (int j = 0; j < 4; ++j) {
            int row = wn * 64 + j * 16 + r0;
            int cc = row * 4 + (gq ^ ((row >> 1) & 3));
            bf[j] = *reinterpret_cast<const bf16x8*>(&Bs[cc * 8]);
        }
#pragma unroll
        for (int i = 0; i < 4; ++i)
#pragma unroll
            for (int j = 0; j < 4; ++j)
                acc[i][j] = __builtin_amdgcn_mfma_f32_16x16x32_bf16(af[i], bf[j], acc[i][j], 0, 0, 0);
        __syncthreads();
    }
}

// rg-merged path: one A tile, two B tiles, 32 MFMA per barrier, K=2048.
__device__ __forceinline__ void kloop_rg(const __hip_bfloat16* __restrict__ A,
                                         const __hip_bfloat16* __restrict__ B1,
                                         const __hip_bfloat16* __restrict__ B2,
                                         __bf16* As, __bf16* Bs1, __bf16* Bs2,
                                         f32x4 accr[4][4], f32x4 accg[4][4],
                                         int t, int wm, int wn, int r0, int gq) {
    for (int k0 = 0; k0 < 2048; k0 += 32) {
#pragma unroll
        for (int p = 0; p < 2; ++p) {
            int c = p * 256 + t;
            int row = c >> 2;
            int jj = ((c & 3) ^ ((row >> 1) & 3)) * 8;
            size_t off = (size_t)row * 2048 + k0 + jj;
            async16(&As[c * 8], A + off);
            async16(&Bs1[c * 8], B1 + off);
            async16(&Bs2[c * 8], B2 + off);
        }
        __syncthreads();
        bf16x8 af[4], b1[4], b2[4];
#pragma unroll
        for (int i = 0; i < 4; ++i) {
            int row = wm * 64 + i * 16 + r0;
            int cc = row * 4 + (gq ^ ((row >> 1) & 3));
            af[i] = *reinterpret_cast<const bf16x8*>(&As[cc * 8]);
        }
#pragma unroll
        for (int j = 0; j < 4; ++j) {
            int row = wn * 64 + j * 16 + r0;
            int cc = row * 4 + (gq ^ ((row >> 1) & 3));
            b1[j] = *reinterpret_cast<const bf16x8*>(&Bs1[cc * 8]);
            b2[j] = *reinterpret_cast<const bf16x8*>(&Bs2[cc * 8]);
        }
#pragma unroll
        for (int i = 0; i < 4; ++i)
#pragma unroll
            for (int j = 0; j < 4; ++j) {
                accr[i][j] = __builtin_amdgcn_mfma_f32_16x16x32_bf16(af[i], b1[j], accr[i][j], 0, 0, 0);
                accg[i][j] = __builtin_amdgcn_mfma_f32_16x16x32_bf16(af[i], b2[j], accg[i][j], 0, 0, 0);
            }
        __syncthreads();
    }
}

// grid (16, 64): nt 0..7 -> rg-merged (c0 = nt*128, long blocks dispatched first);
//                nt 8..15 -> Ucx (c0 = (nt-8)*128).
__global__ __launch_bounds__(256) void gemm_fused(const __hip_bfloat16* __restrict__ xs,
                                                  const __hip_bfloat16* __restrict__ Wt0,
                                                  const __hip_bfloat16* __restrict__ Wt12,
                                                  const float* __restrict__ bias_r,
                                                  const float* __restrict__ bias_g,
                                                  __hip_bfloat16* __restrict__ P) {
    __shared__ __align__(16) __bf16 As[128 * 32];
    __shared__ __align__(16) __bf16 Bs1[128 * 32];
    __shared__ __align__(16) __bf16 Bs2[128 * 32];

    const int nt = blockIdx.x;
    const int mt = blockIdx.y;
    const int mBase = mt * 128;

    const int t = threadIdx.x;
    const int lane = t & 63;
    const int wv = t >> 6;
    const int wm = wv & 1;
    const int wn = wv >> 1;
    const int r0 = lane & 15;
    const int gq = lane >> 4;

    const __hip_bfloat16* A = xs + (size_t)mBase * 2048;

    if (nt < 8) {
        // ---- rg-merged ----
        const int c0 = nt * 128;
        f32x4 accr[4][4], accg[4][4];
        const f32x4 zero = {0.f, 0.f, 0.f, 0.f};
#pragma unroll
        for (int i = 0; i < 4; ++i)
#pragma unroll
            for (int j = 0; j < 4; ++j) { accr[i][j] = zero; accg[i][j] = zero; }

        kloop_rg(A, Wt12 + (size_t)c0 * 2048, Wt12 + (size_t)(1024 + c0) * 2048,
                 As, Bs1, Bs2, accr, accg, t, wm, wn, r0, gq);

        // epilogue: C/D layout col = lane&15, row = (lane>>4)*4 + reg  [m89-verified]
#pragma unroll
        for (int i = 0; i < 4; ++i) {
#pragma unroll
            for (int j = 0; j < 4; ++j) {
#pragma unroll
                for (int reg = 0; reg < 4; ++reg) {
                    int row = mBase + wm * 64 + i * 16 + gq * 4 + reg;
                    int c = c0 + wn * 64 + j * 16 + r0;
                    float zr = 1.0f / (1.0f + __expf(-(accr[i][j][reg] + bias_r[c])));
                    float zg = 1.0f / (1.0f + __expf(-(accg[i][j][reg] + bias_g[c])));
                    bf16x2 pk;
                    pk[0] = (__bf16)zr;
                    pk[1] = (__bf16)zg;
                    *(bf16x2*)((__bf16*)P + (size_t)row * 3072 + 1024 + 2 * c) = pk;  // 4B store
                }
            }
        }
    } else {
        // ---- Ucx ----
        const int c0 = (nt - 8) * 128;
        f32x4 acc[4][4];
        const f32x4 zero = {0.f, 0.f, 0.f, 0.f};
#pragma unroll
        for (int i = 0; i < 4; ++i)
#pragma unroll
            for (int j = 0; j < 4; ++j) acc[i][j] = zero;

        kloop_c(A, Wt0 + (size_t)c0 * 1024, As, Bs1, acc, t, wm, wn, r0, gq);

#pragma unroll
        for (int i = 0; i < 4; ++i) {
#pragma unroll
            for (int j = 0; j < 4; ++j) {
#pragma unroll
                for (int reg = 0; reg < 4; ++reg) {
                    int row = mBase + wm * 64 + i * 16 + gq * 4 + reg;
                    int c = c0 + wn * 64 + j * 16 + r0;
                    P[(size_t)row * 3072 + c] = __float2bfloat16(acc[i][j][reg]);
                }
            }
        }
    }
}

// ---------------- fused butterfly + modReLU + gate ----------------
// Thread t owns cols 4t..4t+3 of 8 rows (all registers).
// Stage H=512: LDS partner t^128; H=256: LDS partner t^64 (3 barriers total).
// Stages H=128..4: __shfl_xor lanemask H/4. Stages H=2,1: in-register permute.
__global__ __launch_bounds__(256) void fuse_kernel(const float* __restrict__ state,
                                                   const __hip_bfloat16* __restrict__ P,
                                                   const float* __restrict__ v1,
                                                   const float* __restrict__ v2,
                                                   const float* __restrict__ bias_c,
                                                   float* __restrict__ out) {
    __shared__ float hbuf[8][1024];
    const int t = threadIdx.x;
    const int rowBase = blockIdx.x * 8;

    float h[8][4];
    float sv[8][4];
#pragma unroll
    for (int r = 0; r < 8; ++r) {
        float4 s4 = ((const float4*)(state + (size_t)(rowBase + r) * 1024))[t];
        h[r][0] = s4.x; h[r][1] = s4.y; h[r][2] = s4.z; h[r][3] = s4.w;
        sv[r][0] = s4.x; sv[r][1] = s4.y; sv[r][2] = s4.z; sv[r][3] = s4.w;
        *(float4*)&hbuf[r][4 * t] = s4;
    }

    // stage 0: H=512, partner thread t^128 (cross-wave -> LDS)
    {
        __syncthreads();
        float4 w1 = *(const float4*)&v1[4 * t];
        float4 w2 = *(const float4*)&v2[4 * (t ^ 128)];
        const float w1v[4] = {w1.x, w1.y, w1.z, w1.w};
        const float w2v[4] = {w2.x, w2.y, w2.z, w2.w};
#pragma unroll
        for (int r = 0; r < 8; ++r) {
            float4 pr = *(const float4*)&hbuf[r][4 * (t ^ 128)];
            const float pv[4] = {pr.x, pr.y, pr.z, pr.w};
#pragma unroll
            for (int e = 0; e < 4; ++e) h[r][e] = h[r][e] * w1v[e] + pv[e] * w2v[e];
        }
        __syncthreads();  // stage-0 reads done before stage-1 writes
    }
    // stage 1: H=256, partner thread t^64 (cross-wave -> LDS)
    {
#pragma unroll
        for (int r = 0; r < 8; ++r)
            *(float4*)&hbuf[r][4 * t] = (float4){h[r][0], h[r][1], h[r][2], h[r][3]};
        __syncthreads();
        float4 w1 = *(const float4*)&v1[1024 + 4 * t];
        float4 w2 = *(const float4*)&v2[1024 + 4 * (t ^ 64)];
        const float w1v[4] = {w1.x, w1.y, w1.z, w1.w};
        const float w2v[4] = {w2.x, w2.y, w2.z, w2.w};
#pragma unroll
        for (int r = 0; r < 8; ++r) {
            float4 pr = *(const float4*)&hbuf[r][4 * (t ^ 64)];
            const float pv[4] = {pr.x, pr.y, pr.z, pr.w};
#pragma unroll
            for (int e = 0; e < 4; ++e) h[r][e] = h[r][e] * w1v[e] + pv[e] * w2v[e];
        }
    }
    // stages 2..7: H=128..4, in-wave shfl_xor with lanemask H/4
#pragma unroll
    for (int i = 2; i <= 7; ++i) {
        const int H = 512 >> i;
        const int lm = H >> 2;  // 32,16,8,4,2,1
        float4 w1 = *(const float4*)&v1[i * 1024 + 4 * t];
        float4 w2 = *(const float4*)&v2[i * 1024 + 4 * (t ^ lm)];
        const float w1v[4] = {w1.x, w1.y, w1.z, w1.w};
        const float w2v[4] = {w2.x, w2.y, w2.z, w2.w};
#pragma unroll
        for (int r = 0; r < 8; ++r) {
#pragma unroll
            for (int e = 0; e < 4; ++e) {
                float p = __shfl_xor(h[r][e], lm, 64);
                h[r][e] = h[r][e] * w1v[e] + p * w2v[e];
            }
        }
    }
    // stage 8: H=2 (element permute e^2); stage 9: H=1 (e^1)
    {
        float4 w1 = *(const float4*)&v1[8 * 1024 + 4 * t];
        float4 w2 = *(const float4*)&v2[8 * 1024 + 4 * t];
        const float w1v[4] = {w1.x, w1.y, w1.z, w1.w};
        const float w2v[4] = {w2.x, w2.y, w2.z, w2.w};
#pragma unroll
        for (int r = 0; r < 8; ++r) {
            float nh[4];
#pragma unroll
            for (int e = 0; e < 4; ++e) nh[e] = h[r][e] * w1v[e] + h[r][e ^ 2] * w2v[e ^ 2];
#pragma unroll
            for (int e = 0; e < 4; ++e) h[r][e] = nh[e];
        }
        float4 u1 = *(const float4*)&v1[9 * 1024 + 4 * t];
        float4 u2 = *(const float4*)&v2[9 * 1024 + 4 * t];
        const float u1v[4] = {u1.x, u1.y, u1.z, u1.w};
        const float u2v[4] = {u2.x, u2.y, u2.z, u2.w};
#pragma unroll
        for (int r = 0; r < 8; ++r) {
            float nh[4];
#pragma unroll
            for (int e = 0; e < 4; ++e) nh[e] = h[r][e] * u1v[e] + h[r][e ^ 1] * u2v[e ^ 1];
#pragma unroll
            for (int e = 0; e < 4; ++e) h[r][e] = nh[e];
        }
    }

    // epilogue: modReLU + gate
    const float4 bc = ((const float4*)bias_c)[t];
    const float bcv[4] = {bc.x, bc.y, bc.z, bc.w};
#pragma unroll
    for (int r = 0; r < 8; ++r) {
        const int row = rowBase + r;
        const __hip_bfloat16* Pr = P + (size_t)row * 3072;
        bf16x4 ux = *(const bf16x4*)((const __bf16*)Pr + 4 * t);        // Ucx, 8 B
        bf16x8 rg = *(const bf16x8*)((const __bf16*)Pr + 1024 + 8 * t); // (r,g) pairs, 16 B
        float o[4];
#pragma unroll
        for (int e = 0; e < 4; ++e) {
            float Ucx = (float)ux[e];
            float rr  = (float)rg[2 * e];
            float gg  = (float)rg[2 * e + 1];
            float pre = rr * h[r][e] + Ucx;
            float mag = fabsf(pre) + 0.001f + bcv[e];
            float c = (pre > 0.f) ? mag : ((pre < 0.f) ? -mag : 0.f);
            o[e] = gg * sv[r][e] + (1.f - gg) * c;
        }
        ((float4*)(out + (size_t)row * 1024))[t] = (float4){o[0], o[1], o[2], o[3]};
    }
}

extern "C" void kernel_launch(void* const* d_in, const int* in_sizes, int n_in,
                              void* d_out, int out_size, void* d_ws, size_t ws_size,
                              hipStream_t stream) {
    const float* x      = (const float*)d_in[0];
    const float* state  = (const float*)d_in[1];
    const float* theta  = (const float*)d_in[2];
    const float* U      = (const float*)d_in[3];
    const float* W_r    = (const float*)d_in[4];
    const float* W_g    = (const float*)d_in[5];
    const float* bias_r = (const float*)d_in[6];
    const float* bias_g = (const float*)d_in[7];
    const float* bias_c = (const float*)d_in[8];
    float* out = (float*)d_out;

    // workspace layout (~90.1 MB)
    __hip_bfloat16* xs   = (__hip_bfloat16*)d_ws;                      // 32 MB
    __hip_bfloat16* Wt0  = xs + (size_t)B_ROWS * 2048;                 // 2 MB
    __hip_bfloat16* Wt12 = Wt0 + (size_t)1024 * 1024;                  // 8 MB
    __hip_bfloat16* P    = Wt12 + (size_t)2048 * 2048;                 // 48 MB
    float* v1 = (float*)(P + (size_t)B_ROWS * 3072);                   // 40 KB
    float* v2 = v1 + 10 * 1024;                                        // 40 KB

    prep_all<<<13352, 256, 0, stream>>>(x, state, theta, U, W_r, W_g, xs, Wt0, Wt12, v1, v2);
    gemm_fused<<<dim3(16, 64), 256, 0, stream>>>(xs, Wt0, Wt12, bias_r, bias_g, P);
    fuse_kernel<<<1024, 256, 0, stream>>>(state, P, v1, v2, bias_c, out);
}

// Round 6
// 282.514 us; speedup vs baseline: 1.4513x; 1.4513x over previous
//
#include <hip/hip_runtime.h>
#include <hip/hip_bf16.h>
#include <stdint.h>

// GORU fused cell. B=8192, IN=1024, D=1024, CAP=10.
// 3 launches:
//   prep_all : xs[8192][2048] bf16 = [bf16(x)|bf16(state)];
//              Wt0[1024][1024]=U_c^T; Wt12[2048][2048]=[[U_r^T|W_r^T],[U_g^T|W_g^T]];
//              v1/v2[10][1024] butterfly tables
//   gemm     : P[8192][3072] bf16 = { Ucx , interleaved (r,g) }
//              512-thread blocks / 8 waves (64x32 per wave per output -> 64 acc VGPRs).
//              nt<8: rg-merged (one A tile, two B tiles, 128 MFMA per 24KB staged);
//              nt>=8: Ucx (K=1024). BK=32, zero-conflict XOR swizzle (r4-verified).
//   fuse     : out = g*state + (1-g)*modReLU(r*butterfly(state) + Ucx)

typedef __bf16 bf16x8 __attribute__((ext_vector_type(8)));
typedef __bf16 bf16x4 __attribute__((ext_vector_type(4)));
typedef __bf16 bf16x2 __attribute__((ext_vector_type(2)));
typedef float f32x4 __attribute__((ext_vector_type(4)));

#define B_ROWS 8192

__device__ __forceinline__ void async16(__bf16* lds, const __hip_bfloat16* g) {
    __builtin_amdgcn_global_load_lds((const __attribute__((address_space(1))) void*)g,
                                     (__attribute__((address_space(3))) void*)lds,
                                     16, 0, 0);
}

// ---------------- prep_all: blockIdx-partitioned (xs cast | weight transpose | tables) ----------------
__global__ __launch_bounds__(256) void prep_all(const float* __restrict__ x,
                                                const float* __restrict__ state,
                                                const float* __restrict__ theta,
                                                const float* __restrict__ U,
                                                const float* __restrict__ Wr,
                                                const float* __restrict__ Wg,
                                                __hip_bfloat16* __restrict__ xs,
                                                __hip_bfloat16* __restrict__ Wt0,
                                                __hip_bfloat16* __restrict__ Wt12,
                                                float* __restrict__ v1,
                                                float* __restrict__ v2) {
    __shared__ float tile[32][33];
    const int id = blockIdx.x;
    if (id < 8192) {
        // --- xs = [bf16(x) | bf16(state)] ---
        const int row = id;
        const int col = threadIdx.x * 8;  // 0..2040
        const float* src = (col < 1024) ? (x + (size_t)row * 1024 + col)
                                        : (state + (size_t)row * 1024 + (col - 1024));
        float4 a = *(const float4*)src;
        float4 b = *(const float4*)(src + 4);
        bf16x8 v;
        v[0] = (__bf16)a.x; v[1] = (__bf16)a.y; v[2] = (__bf16)a.z; v[3] = (__bf16)a.w;
        v[4] = (__bf16)b.x; v[5] = (__bf16)b.y; v[6] = (__bf16)b.z; v[7] = (__bf16)b.w;
        *(bf16x8*)((__bf16*)xs + (size_t)row * 2048 + col) = v;
    } else if (id < 13312) {
        // --- weight transpose+cast ---
        const int wid = id - 8192;
        const float* src; int srcN, scol, sk;
        __hip_bfloat16* dst; int dstStride, dn, dk;
        if (wid < 1024) {
            int nx = wid & 31, ky = wid >> 5;
            src = U; srcN = 3072; scol = nx * 32; sk = ky * 32;
            dst = Wt0; dstStride = 1024; dn = nx * 32; dk = ky * 32;
        } else {
            int id2 = wid - 1024;
            int nx = id2 & 63, ky = id2 >> 6;
            int n0 = nx * 32, k0 = ky * 32;
            dst = Wt12; dstStride = 2048; dn = n0; dk = k0;
            if (k0 < 1024)      { src = U;  srcN = 3072; scol = 1024 + n0; sk = k0; }
            else if (n0 < 1024) { src = Wr; srcN = 1024; scol = n0;        sk = k0 - 1024; }
            else                { src = Wg; srcN = 1024; scol = n0 - 1024; sk = k0 - 1024; }
        }
        const int tx = threadIdx.x & 31, ty = threadIdx.x >> 5;
#pragma unroll
        for (int s = 0; s < 4; ++s)
            tile[ty + s * 8][tx] = src[(size_t)(sk + ty + s * 8) * srcN + scol + tx];
        __syncthreads();
#pragma unroll
        for (int s = 0; s < 4; ++s)
            dst[(size_t)(dn + ty + s * 8) * dstStride + dk + tx] = __float2bfloat16(tile[tx][ty + s * 8]);
    } else {
        // --- butterfly tables ---
        // v1[i][j]=cos(theta[i][q&511]); v2[i][j]=(q<512?+sin:-sin), q=m*2^i+j0,
        // j0=j>>(10-i), m=j&((1024>>i)-1).
        int idx = (id - 13312) * 256 + threadIdx.x;  // 10240 total
        int i = idx >> 10;
        int j = idx & 1023;
        int Q = 1024 >> i;
        int j0 = j / Q;
        int m = j & (Q - 1);
        int q = (m << i) + j0;
        float th = theta[i * 512 + (q & 511)];
        float c = cosf(th);
        float s = sinf(th);
        v1[idx] = c;
        v2[idx] = (q < 512) ? s : -s;
    }
}

// ---------------- GEMM: 512 threads / 8 waves per block ----------------
// Zero-conflict swizzle (r4-verified): LDS chunk c holds global (row=c>>2, k-chunk (c&3)^((row>>1)&3));
// read cc = row*4 + (gq ^ ((row>>1)&3)).
// Wave layout: wv = t>>6 in [0,8); wm = wv&1 (64-row half), wn = wv>>1 (32-col quarter).
// grid (16, 64): nt<8 -> rg-merged (c0=nt*128, K=2048); nt>=8 -> Ucx (c0=(nt-8)*128, K=1024).
__global__ __launch_bounds__(512, 4) void gemm_fused(const __hip_bfloat16* __restrict__ xs,
                                                     const __hip_bfloat16* __restrict__ Wt0,
                                                     const __hip_bfloat16* __restrict__ Wt12,
                                                     const float* __restrict__ bias_r,
                                                     const float* __restrict__ bias_g,
                                                     __hip_bfloat16* __restrict__ P) {
    __shared__ __align__(16) __bf16 As[128 * 32];
    __shared__ __align__(16) __bf16 Bs1[128 * 32];
    __shared__ __align__(16) __bf16 Bs2[128 * 32];

    const int nt = blockIdx.x;
    const int mt = blockIdx.y;
    const int mBase = mt * 128;

    const int t = threadIdx.x;          // 0..511
    const int lane = t & 63;
    const int wv = t >> 6;              // 0..7
    const int wm = wv & 1;
    const int wn = wv >> 1;             // 0..3
    const int r0 = lane & 15;
    const int gq = lane >> 4;

    // staging indices (one 16B chunk per thread per array)
    const int srow = t >> 2;                          // 0..127
    const int sjj = ((t & 3) ^ ((srow >> 1) & 3)) * 8;

    const __hip_bfloat16* A = xs + (size_t)mBase * 2048;

    if (nt < 8) {
        // ---- rg-merged: K=2048, one A tile, two B tiles, 128 MFMA per barrier ----
        const int c0 = nt * 128;
        const __hip_bfloat16* B1 = Wt12 + (size_t)c0 * 2048;
        const __hip_bfloat16* B2 = Wt12 + (size_t)(1024 + c0) * 2048;

        f32x4 accr[4][2], accg[4][2];
        const f32x4 zero = {0.f, 0.f, 0.f, 0.f};
#pragma unroll
        for (int i = 0; i < 4; ++i)
#pragma unroll
            for (int j = 0; j < 2; ++j) { accr[i][j] = zero; accg[i][j] = zero; }

        for (int k0 = 0; k0 < 2048; k0 += 32) {
            size_t off = (size_t)srow * 2048 + k0 + sjj;
            async16(&As[t * 8], A + off);
            async16(&Bs1[t * 8], B1 + off);
            async16(&Bs2[t * 8], B2 + off);
            __syncthreads();

            bf16x8 af[4], b1[2], b2[2];
#pragma unroll
            for (int i = 0; i < 4; ++i) {
                int row = wm * 64 + i * 16 + r0;
                int cc = row * 4 + (gq ^ ((row >> 1) & 3));
                af[i] = *reinterpret_cast<const bf16x8*>(&As[cc * 8]);
            }
#pragma unroll
            for (int j = 0; j < 2; ++j) {
                int row = wn * 32 + j * 16 + r0;
                int cc = row * 4 + (gq ^ ((row >> 1) & 3));
                b1[j] = *reinterpret_cast<const bf16x8*>(&Bs1[cc * 8]);
                b2[j] = *reinterpret_cast<const bf16x8*>(&Bs2[cc * 8]);
            }
#pragma unroll
            for (int i = 0; i < 4; ++i)
#pragma unroll
                for (int j = 0; j < 2; ++j) {
                    accr[i][j] = __builtin_amdgcn_mfma_f32_16x16x32_bf16(af[i], b1[j], accr[i][j], 0, 0, 0);
                    accg[i][j] = __builtin_amdgcn_mfma_f32_16x16x32_bf16(af[i], b2[j], accg[i][j], 0, 0, 0);
                }
            __syncthreads();
        }

        // epilogue: C/D layout col = lane&15, row = (lane>>4)*4 + reg  [m89-verified]
#pragma unroll
        for (int i = 0; i < 4; ++i) {
#pragma unroll
            for (int j = 0; j < 2; ++j) {
#pragma unroll
                for (int reg = 0; reg < 4; ++reg) {
                    int row = mBase + wm * 64 + i * 16 + gq * 4 + reg;
                    int c = c0 + wn * 32 + j * 16 + r0;
                    float zr = 1.0f / (1.0f + __expf(-(accr[i][j][reg] + bias_r[c])));
                    float zg = 1.0f / (1.0f + __expf(-(accg[i][j][reg] + bias_g[c])));
                    bf16x2 pk;
                    pk[0] = (__bf16)zr;
                    pk[1] = (__bf16)zg;
                    *(bf16x2*)((__bf16*)P + (size_t)row * 3072 + 1024 + 2 * c) = pk;  // 4B store
                }
            }
        }
    } else {
        // ---- Ucx: K=1024 ----
        const int c0 = (nt - 8) * 128;
        const __hip_bfloat16* Bb = Wt0 + (size_t)c0 * 1024;

        f32x4 acc[4][2];
        const f32x4 zero = {0.f, 0.f, 0.f, 0.f};
#pragma unroll
        for (int i = 0; i < 4; ++i)
#pragma unroll
            for (int j = 0; j < 2; ++j) acc[i][j] = zero;

        for (int k0 = 0; k0 < 1024; k0 += 32) {
            async16(&As[t * 8], A + (size_t)srow * 2048 + k0 + sjj);
            async16(&Bs1[t * 8], Bb + (size_t)srow * 1024 + k0 + sjj);
            __syncthreads();

            bf16x8 af[4], bf[2];
#pragma unroll
            for (int i = 0; i < 4; ++i) {
                int row = wm * 64 + i * 16 + r0;
                int cc = row * 4 + (gq ^ ((row >> 1) & 3));
                af[i] = *reinterpret_cast<const bf16x8*>(&As[cc * 8]);
            }
#pragma unroll
            for (int j = 0; j < 2; ++j) {
                int row = wn * 32 + j * 16 + r0;
                int cc = row * 4 + (gq ^ ((row >> 1) & 3));
                bf[j] = *reinterpret_cast<const bf16x8*>(&Bs1[cc * 8]);
            }
#pragma unroll
            for (int i = 0; i < 4; ++i)
#pragma unroll
                for (int j = 0; j < 2; ++j)
                    acc[i][j] = __builtin_amdgcn_mfma_f32_16x16x32_bf16(af[i], bf[j], acc[i][j], 0, 0, 0);
            __syncthreads();
        }

#pragma unroll
        for (int i = 0; i < 4; ++i) {
#pragma unroll
            for (int j = 0; j < 2; ++j) {
#pragma unroll
                for (int reg = 0; reg < 4; ++reg) {
                    int row = mBase + wm * 64 + i * 16 + gq * 4 + reg;
                    int c = c0 + wn * 32 + j * 16 + r0;
                    P[(size_t)row * 3072 + c] = __float2bfloat16(acc[i][j][reg]);
                }
            }
        }
    }
}

// ---------------- fused butterfly + modReLU + gate ----------------
// Thread t owns cols 4t..4t+3 of 8 rows (all registers).
// Stage H=512: LDS partner t^128; H=256: LDS partner t^64 (3 barriers total).
// Stages H=128..4: __shfl_xor lanemask H/4. Stages H=2,1: in-register permute.
__global__ __launch_bounds__(256) void fuse_kernel(const float* __restrict__ state,
                                                   const __hip_bfloat16* __restrict__ P,
                                                   const float* __restrict__ v1,
                                                   const float* __restrict__ v2,
                                                   const float* __restrict__ bias_c,
                                                   float* __restrict__ out) {
    __shared__ float hbuf[8][1024];
    const int t = threadIdx.x;
    const int rowBase = blockIdx.x * 8;

    float h[8][4];
    float sv[8][4];
#pragma unroll
    for (int r = 0; r < 8; ++r) {
        float4 s4 = ((const float4*)(state + (size_t)(rowBase + r) * 1024))[t];
        h[r][0] = s4.x; h[r][1] = s4.y; h[r][2] = s4.z; h[r][3] = s4.w;
        sv[r][0] = s4.x; sv[r][1] = s4.y; sv[r][2] = s4.z; sv[r][3] = s4.w;
        *(float4*)&hbuf[r][4 * t] = s4;
    }

    // stage 0: H=512, partner thread t^128 (cross-wave -> LDS)
    {
        __syncthreads();
        float4 w1 = *(const float4*)&v1[4 * t];
        float4 w2 = *(const float4*)&v2[4 * (t ^ 128)];
        const float w1v[4] = {w1.x, w1.y, w1.z, w1.w};
        const float w2v[4] = {w2.x, w2.y, w2.z, w2.w};
#pragma unroll
        for (int r = 0; r < 8; ++r) {
            float4 pr = *(const float4*)&hbuf[r][4 * (t ^ 128)];
            const float pv[4] = {pr.x, pr.y, pr.z, pr.w};
#pragma unroll
            for (int e = 0; e < 4; ++e) h[r][e] = h[r][e] * w1v[e] + pv[e] * w2v[e];
        }
        __syncthreads();  // stage-0 reads done before stage-1 writes
    }
    // stage 1: H=256, partner thread t^64 (cross-wave -> LDS)
    {
#pragma unroll
        for (int r = 0; r < 8; ++r)
            *(float4*)&hbuf[r][4 * t] = (float4){h[r][0], h[r][1], h[r][2], h[r][3]};
        __syncthreads();
        float4 w1 = *(const float4*)&v1[1024 + 4 * t];
        float4 w2 = *(const float4*)&v2[1024 + 4 * (t ^ 64)];
        const float w1v[4] = {w1.x, w1.y, w1.z, w1.w};
        const float w2v[4] = {w2.x, w2.y, w2.z, w2.w};
#pragma unroll
        for (int r = 0; r < 8; ++r) {
            float4 pr = *(const float4*)&hbuf[r][4 * (t ^ 64)];
            const float pv[4] = {pr.x, pr.y, pr.z, pr.w};
#pragma unroll
            for (int e = 0; e < 4; ++e) h[r][e] = h[r][e] * w1v[e] + pv[e] * w2v[e];
        }
    }
    // stages 2..7: H=128..4, in-wave shfl_xor with lanemask H/4
#pragma unroll
    for (int i = 2; i <= 7; ++i) {
        const int H = 512 >> i;
        const int lm = H >> 2;  // 32,16,8,4,2,1
        float4 w1 = *(const float4*)&v1[i * 1024 + 4 * t];
        float4 w2 = *(const float4*)&v2[i * 1024 + 4 * (t ^ lm)];
        const float w1v[4] = {w1.x, w1.y, w1.z, w1.w};
        const float w2v[4] = {w2.x, w2.y, w2.z, w2.w};
#pragma unroll
        for (int r = 0; r < 8; ++r) {
#pragma unroll
            for (int e = 0; e < 4; ++e) {
                float p = __shfl_xor(h[r][e], lm, 64);
                h[r][e] = h[r][e] * w1v[e] + p * w2v[e];
            }
        }
    }
    // stage 8: H=2 (element permute e^2); stage 9: H=1 (e^1)
    {
        float4 w1 = *(const float4*)&v1[8 * 1024 + 4 * t];
        float4 w2 = *(const float4*)&v2[8 * 1024 + 4 * t];
        const float w1v[4] = {w1.x, w1.y, w1.z, w1.w};
        const float w2v[4] = {w2.x, w2.y, w2.z, w2.w};
#pragma unroll
        for (int r = 0; r < 8; ++r) {
            float nh[4];
#pragma unroll
            for (int e = 0; e < 4; ++e) nh[e] = h[r][e] * w1v[e] + h[r][e ^ 2] * w2v[e ^ 2];
#pragma unroll
            for (int e = 0; e < 4; ++e) h[r][e] = nh[e];
        }
        float4 u1 = *(const float4*)&v1[9 * 1024 + 4 * t];
        float4 u2 = *(const float4*)&v2[9 * 1024 + 4 * t];
        const float u1v[4] = {u1.x, u1.y, u1.z, u1.w};
        const float u2v[4] = {u2.x, u2.y, u2.z, u2.w};
#pragma unroll
        for (int r = 0; r < 8; ++r) {
            float nh[4];
#pragma unroll
            for (int e = 0; e < 4; ++e) nh[e] = h[r][e] * u1v[e] + h[r][e ^ 1] * u2v[e ^ 1];
#pragma unroll
            for (int e = 0; e < 4; ++e) h[r][e] = nh[e];
        }
    }

    // epilogue: modReLU + gate
    const float4 bc = ((const float4*)bias_c)[t];
    const float bcv[4] = {bc.x, bc.y, bc.z, bc.w};
#pragma unroll
    for (int r = 0; r < 8; ++r) {
        const int row = rowBase + r;
        const __hip_bfloat16* Pr = P + (size_t)row * 3072;
        bf16x4 ux = *(const bf16x4*)((const __bf16*)Pr + 4 * t);        // Ucx, 8 B
        bf16x8 rg = *(const bf16x8*)((const __bf16*)Pr + 1024 + 8 * t); // (r,g) pairs, 16 B
        float o[4];
#pragma unroll
        for (int e = 0; e < 4; ++e) {
            float Ucx = (float)ux[e];
            float rr  = (float)rg[2 * e];
            float gg  = (float)rg[2 * e + 1];
            float pre = rr * h[r][e] + Ucx;
            float mag = fabsf(pre) + 0.001f + bcv[e];
            float c = (pre > 0.f) ? mag : ((pre < 0.f) ? -mag : 0.f);
            o[e] = gg * sv[r][e] + (1.f - gg) * c;
        }
        ((float4*)(out + (size_t)row * 1024))[t] = (float4){o[0], o[1], o[2], o[3]};
    }
}

extern "C" void kernel_launch(void* const* d_in, const int* in_sizes, int n_in,
                              void* d_out, int out_size, void* d_ws, size_t ws_size,
                              hipStream_t stream) {
    const float* x      = (const float*)d_in[0];
    const float* state  = (const float*)d_in[1];
    const float* theta  = (const float*)d_in[2];
    const float* U      = (const float*)d_in[3];
    const float* W_r    = (const float*)d_in[4];
    const float* W_g    = (const float*)d_in[5];
    const float* bias_r = (const float*)d_in[6];
    const float* bias_g = (const float*)d_in[7];
    const float* bias_c = (const float*)d_in[8];
    float* out = (float*)d_out;

    // workspace layout (~90.1 MB)
    __hip_bfloat16* xs   = (__hip_bfloat16*)d_ws;                      // 32 MB
    __hip_bfloat16* Wt0  = xs + (size_t)B_ROWS * 2048;                 // 2 MB
    __hip_bfloat16* Wt12 = Wt0 + (size_t)1024 * 1024;                  // 8 MB
    __hip_bfloat16* P    = Wt12 + (size_t)2048 * 2048;                 // 48 MB
    float* v1 = (float*)(P + (size_t)B_ROWS * 3072);                   // 40 KB
    float* v2 = v1 + 10 * 1024;                                        // 40 KB

    prep_all<<<13352, 256, 0, stream>>>(x, state, theta, U, W_r, W_g, xs, Wt0, Wt12, v1, v2);
    gemm_fused<<<dim3(16, 64), 512, 0, stream>>>(xs, Wt0, Wt12, bias_r, bias_g, P);
    fuse_kernel<<<1024, 256, 0, stream>>>(state, P, v1, v2, bias_c, out);
}